// Round 6
// baseline (301.791 us; speedup 1.0000x reference)
//
#include <hip/hip_runtime.h>

typedef __attribute__((ext_vector_type(8))) short s16x8;
typedef __attribute__((ext_vector_type(4))) short s16x4;
typedef __attribute__((ext_vector_type(4))) float f32x4;
typedef unsigned short u16;
typedef unsigned int u32;
typedef unsigned long long u64;

__device__ __forceinline__ u16 f2bf(float f) {
  unsigned u = __builtin_bit_cast(unsigned, f);
  return (u16)((u + 0x7fffu + ((u >> 16) & 1u)) >> 16);  // RNE fp32->bf16
}

// 0.125 (1/sqrt(dh)) * log2(e): scores in log2 domain for v_exp_f32
#define QSCALE 0.18033688011112042f

// async global->LDS, 16B per lane; LDS dst = wave-uniform base + lane*16
__device__ __forceinline__ void gld16(const u16* g, u16* l) {
  __builtin_amdgcn_global_load_lds(
      (const __attribute__((address_space(1))) void*)g,
      (__attribute__((address_space(3))) void*)l, 16, 0, 0);
}

// v_perm: D = [bf16(a) | bf16(b)<<16] by byte-select (truncating pack, 1 op)
__device__ __forceinline__ u32 pack_trunc(float a, float b) {
  return __builtin_amdgcn_perm(__builtin_bit_cast(u32, b),
                               __builtin_bit_cast(u32, a), 0x07060302u);
}

// ---------------------------------------------------------------------------
// fp32 -> bf16 convert, all five tensors in ONE launch (saves 4 launches).
// blocks [0,4096): x (1048576 groups); then 512 blocks per W.
// ---------------------------------------------------------------------------
__global__ __launch_bounds__(256)
void cvt_all(const float* __restrict__ x,  u16* __restrict__ xb,
             const float* __restrict__ w0, u16* __restrict__ w0b,
             const float* __restrict__ w1, u16* __restrict__ w1b,
             const float* __restrict__ w2, u16* __restrict__ w2b,
             const float* __restrict__ w3, u16* __restrict__ w3b)
{
  int bb = blockIdx.x;
  const float* src; u16* dst; int i;
  if (bb < 4096)      { src = x;  dst = xb;  i = bb * 256 + threadIdx.x; }
  else if (bb < 4608) { src = w0; dst = w0b; i = (bb - 4096) * 256 + threadIdx.x; }
  else if (bb < 5120) { src = w1; dst = w1b; i = (bb - 4608) * 256 + threadIdx.x; }
  else if (bb < 5632) { src = w2; dst = w2b; i = (bb - 5120) * 256 + threadIdx.x; }
  else                { src = w3; dst = w3b; i = (bb - 5632) * 256 + threadIdx.x; }
  f32x4 a = ((const f32x4*)src)[2 * i];
  f32x4 b = ((const f32x4*)src)[2 * i + 1];
  s16x8 pk;
  pk[0] = (short)f2bf(a[0]); pk[1] = (short)f2bf(a[1]);
  pk[2] = (short)f2bf(a[2]); pk[3] = (short)f2bf(a[3]);
  pk[4] = (short)f2bf(b[0]); pk[5] = (short)f2bf(b[1]);
  pk[6] = (short)f2bf(b[2]); pk[7] = (short)f2bf(b[3]);
  ((s16x8*)dst)[i] = pk;
}

// ---------------------------------------------------------------------------
// m97-structure GEMM. Grid: (m-tiles, n-tiles, z); m-tile on x -> XCD-pinned.
// OUT_QKV: bz=0 -> Q [b,h,s,dh] (scaled); bz=1 -> K [b,h,s,dh];
//          bz=2 -> V TRANSPOSED [b,h,dh,s] (folds the old vtrans kernel).
// ---------------------------------------------------------------------------
template<bool OUT_QKV>
__global__ __launch_bounds__(256)
void gemm97(const u16* __restrict__ A,
            const u16* __restrict__ B0, const u16* __restrict__ B1,
            const u16* __restrict__ B2,
            u16* __restrict__ o0, u16* __restrict__ o1, u16* __restrict__ o2,
            float* __restrict__ oF)
{
  const int by = blockIdx.x;   // m-tile (XCD-pinned)
  const int bx = blockIdx.y;   // n-tile
  const int bz = blockIdx.z;
  const u16* B = (bz == 0) ? B0 : ((bz == 1) ? B1 : B2);
  u16* oQ = (bz == 0) ? o0 : ((bz == 1) ? o1 : o2);

  __shared__ u16 As[128 * 32];
  __shared__ u16 Bs[128 * 32];

  const int tid  = threadIdx.x;
  const int w    = tid >> 6;
  const int lane = tid & 63;
  const int quad = lane >> 4;
  const int l15  = lane & 15;
  const int wm   = (w >> 1) * 64;
  const int wn   = (w & 1) * 64;

  const int arb  = w * 32;
  const int srow = lane >> 2;
  const int scol = (lane & 3) * 8;
  const u16* ga = A + (size_t)(by * 128 + arb + srow) * 1024 + scol;
  const u16* gb = B + (size_t)(bx * 128 + arb + srow) * 1024 + scol;
  u16* la0 = &As[arb * 32];
  u16* la1 = &As[(arb + 16) * 32];
  u16* lb0 = &Bs[arb * 32];
  u16* lb1 = &Bs[(arb + 16) * 32];

  f32x4 acc[4][4];
  #pragma unroll
  for (int i = 0; i < 4; ++i)
    #pragma unroll
    for (int j = 0; j < 4; ++j)
      acc[i][j] = (f32x4){0.f, 0.f, 0.f, 0.f};

  for (int k0 = 0; k0 < 1024; k0 += 32) {
    gld16(ga + k0,               la0);
    gld16(ga + k0 + 16 * 1024,   la1);
    gld16(gb + k0,               lb0);
    gld16(gb + k0 + 16 * 1024,   lb1);
    __syncthreads();

    s16x8 af[4], bf[4];
    #pragma unroll
    for (int i = 0; i < 4; ++i)
      af[i] = *(const s16x8*)&As[(wm + i * 16 + l15) * 32 + quad * 8];
    #pragma unroll
    for (int i = 0; i < 4; ++i)
      bf[i] = *(const s16x8*)&Bs[(wn + i * 16 + l15) * 32 + quad * 8];
    #pragma unroll
    for (int mt = 0; mt < 4; ++mt)
      #pragma unroll
      for (int nt = 0; nt < 4; ++nt)
        acc[mt][nt] = __builtin_amdgcn_mfma_f32_16x16x32_bf16(
            af[mt], bf[nt], acc[mt][nt], 0, 0, 0);
    __syncthreads();
  }

  #pragma unroll
  for (int mt = 0; mt < 4; ++mt)
    #pragma unroll
    for (int nt = 0; nt < 4; ++nt)
      #pragma unroll
      for (int r = 0; r < 4; ++r) {
        const int row = by * 128 + wm + mt * 16 + quad * 4 + r;
        const int col = bx * 128 + wn + nt * 16 + l15;
        float v = acc[mt][nt][r];
        if (OUT_QKV) {
          const int b = row >> 11, s = row & 2047, hh = col >> 6, d = col & 63;
          if (bz == 2) {  // V: write transposed [b,h,dh,s]
            oQ[(size_t)(b * 16 + hh) * 131072 + d * 2048 + s] = f2bf(v);
          } else {
            if (bz == 0) v *= QSCALE;
            oQ[(size_t)(b * 16 + hh) * 131072 + s * 64 + d] = f2bf(v);
          }
        } else {
          oF[(size_t)row * 1024 + col] = v;
        }
      }
}

// ---------------------------------------------------------------------------
// Causal flash attention. Block pi owns q-tiles {31-pi, pi}; every wave
// processes 16 rows of each (compile-time tile index via ATTN_STEP macro).
// K and V^T staged via global_load_lds width=16 into stride-32 u16 panels
// (the proven m97 conflict-free layout); the K slot permutation
// slot=(key&3)*16+(key>>2) is folded into the per-lane GLOBAL address
// (key=(lane>>2)*4+w), so lane l15's 4 S-columns are keys 4*l15..+3 and
// P row-stores are single u64 writes. Q/P rows stride 68 (2-way max).
// LDS 33.8KB -> 4 blocks/CU.
// ---------------------------------------------------------------------------
#define ATTN_STEP(t, Pw, qtt)                                                  \
  do {                                                                         \
    f32x4 S[4];                                                                \
    _Pragma("unroll")                                                          \
    for (int nt = 0; nt < 4; ++nt) {                                           \
      s16x8 b0 = *(const s16x8*)&Ks[(nt * 16 + l15) * 32 + quad * 8];          \
      s16x8 b1 = *(const s16x8*)&Ks[2048 + (nt * 16 + l15) * 32 + quad * 8];   \
      f32x4 z = (f32x4){0.f, 0.f, 0.f, 0.f};                                   \
      z = __builtin_amdgcn_mfma_f32_16x16x32_bf16(aq[t][0], b0, z, 0, 0, 0);   \
      z = __builtin_amdgcn_mfma_f32_16x16x32_bf16(aq[t][1], b1, z, 0, 0, 0);   \
      S[nt] = z;                                                               \
    }                                                                          \
    if (j == (qtt)) {                                                          \
      _Pragma("unroll")                                                        \
      for (int nt = 0; nt < 4; ++nt)                                           \
        _Pragma("unroll")                                                      \
        for (int r = 0; r < 4; ++r) {                                          \
          const int kg = 4 * l15 + nt;                                         \
          const int qg = w * 16 + quad * 4 + r;                                \
          if (kg > qg) S[nt][r] = -1e30f;                                      \
        }                                                                      \
    }                                                                          \
    _Pragma("unroll")                                                          \
    for (int r = 0; r < 4; ++r) {                                              \
      float rm = fmaxf(fmaxf(S[0][r], S[1][r]), fmaxf(S[2][r], S[3][r]));      \
      _Pragma("unroll")                                                        \
      for (int off = 1; off < 16; off <<= 1)                                   \
        rm = fmaxf(rm, __shfl_xor(rm, off, 64));                               \
      const float mold = mi[t][r];                                             \
      const float mnew = fmaxf(mold, rm);                                      \
      const float alpha = __builtin_amdgcn_exp2f(mold - mnew);                 \
      mi[t][r] = mnew;                                                         \
      const float p0 = __builtin_amdgcn_exp2f(S[0][r] - mnew);                 \
      const float p1 = __builtin_amdgcn_exp2f(S[1][r] - mnew);                 \
      const float p2 = __builtin_amdgcn_exp2f(S[2][r] - mnew);                 \
      const float p3 = __builtin_amdgcn_exp2f(S[3][r] - mnew);                 \
      liacc[t][r] *= alpha;                                                    \
      _Pragma("unroll")                                                        \
      for (int dt = 0; dt < 4; ++dt) O[t][dt][r] *= alpha;                     \
      const u64 pk = (u64)pack_trunc(p0, p1) |                                 \
                     ((u64)pack_trunc(p2, p3) << 32);                          \
      *(u64*)&(Pw)[(quad * 4 + r) * 68 + 4 * l15] = pk;                        \
    }                                                                          \
    s16x8 a0 = *(const s16x8*)&(Pw)[l15 * 68 + quad * 8];                      \
    s16x8 a1 = *(const s16x8*)&(Pw)[l15 * 68 + 32 + quad * 8];                 \
    liacc[t] = __builtin_amdgcn_mfma_f32_16x16x32_bf16(a0, ones, liacc[t], 0, 0, 0); \
    liacc[t] = __builtin_amdgcn_mfma_f32_16x16x32_bf16(a1, ones, liacc[t], 0, 0, 0); \
    _Pragma("unroll")                                                          \
    for (int dt = 0; dt < 4; ++dt) {                                           \
      s16x8 b0 = *(const s16x8*)&Vt[(dt * 16 + l15) * 32 + quad * 8];          \
      s16x8 b1 = *(const s16x8*)&Vt[2048 + (dt * 16 + l15) * 32 + quad * 8];   \
      O[t][dt] = __builtin_amdgcn_mfma_f32_16x16x32_bf16(a0, b0, O[t][dt], 0, 0, 0); \
      O[t][dt] = __builtin_amdgcn_mfma_f32_16x16x32_bf16(a1, b1, O[t][dt], 0, 0, 0); \
    }                                                                          \
  } while (0)

__global__ __launch_bounds__(256, 4)
void attn_kernel(const u16* __restrict__ Qg, const u16* __restrict__ Kg,
                 const u16* __restrict__ VTg, u16* __restrict__ out)
{
  const int pi = blockIdx.x;
  const int bh = blockIdx.y;
  const int b = bh >> 4, h = bh & 15;
  const int qt0 = 31 - pi;            // heavy tile
  const int qt1 = pi;                 // light tile

  __shared__ u16 Qs[128 * 68];        // rows 0-63: qt0, 64-127: qt1; P scratch
  __shared__ u16 Ks[2 * 64 * 32];     // panel p: dh 32p..32p+31; rows = slots
  __shared__ u16 Vt[2 * 64 * 32];     // panel p: keys 32p..32p+31; rows = dh

  const int tid = threadIdx.x;
  const int w = tid >> 6, lane = tid & 63, quad = lane >> 4, l15 = lane & 15;
  const size_t base = (size_t)bh * 131072;

  // stage Q (once, scalar): rows 0-63 = qt0, 64-127 = qt1; stride 68
  {
    const int col = (tid & 7) * 8;
    #pragma unroll
    for (int p = 0; p < 4; ++p) {
      const int row = (tid >> 3) + p * 32;
      const int gq = (row < 64) ? (qt0 * 64 + row) : (qt1 * 64 + (row - 64));
      *(s16x8*)&Qs[row * 68 + col] =
          *(const s16x8*)(Qg + base + (size_t)gq * 64 + col);
    }
  }
  __syncthreads();

  s16x8 aq[2][2];
  #pragma unroll
  for (int t = 0; t < 2; ++t)
    #pragma unroll
    for (int ks = 0; ks < 2; ++ks)
      aq[t][ks] = *(const s16x8*)&Qs[(t * 64 + w * 16 + l15) * 68 + ks * 32 + quad * 8];

  u16* Pw0 = &Qs[(w * 16) * 68];
  u16* Pw1 = &Qs[(64 + w * 16) * 68];

  s16x8 ones;
  #pragma unroll
  for (int e = 0; e < 8; ++e) ones[e] = (short)0x3F80;

  f32x4 O[2][4], liacc[2];
  float mi[2][4];
  #pragma unroll
  for (int t = 0; t < 2; ++t) {
    #pragma unroll
    for (int dt = 0; dt < 4; ++dt) O[t][dt] = (f32x4){0.f, 0.f, 0.f, 0.f};
    liacc[t] = (f32x4){0.f, 0.f, 0.f, 0.f};
    #pragma unroll
    for (int r = 0; r < 4; ++r) mi[t][r] = -1e30f;
  }

  // gld16 staging maps (per wave w):
  //   K: slot = w*16 + (lane>>2)  -> key = (lane>>2)*4 + w  (permutation in
  //      the global address); panel p = dh half. LDS: Ks[p*2048 + slot*32].
  //   V: d = w*16 + (lane>>2); panel p = key half. LDS: Vt[p*2048 + d*32].
  const int kkey   = (lane >> 2) * 4 + w;       // key staged by this lane (K)
  const int vd     = w * 16 + (lane >> 2);      // dh row staged by this lane (V)
  const int chunk  = (lane & 3) * 8;            // 16B chunk within 32-u16 row
  const u16* gk = Kg  + base + (size_t)kkey * 64 + chunk;   // + j*64*64 per iter
  const u16* gv = VTg + base + (size_t)vd * 2048 + chunk;   // + j*64 per iter
  u16* lk0 = &Ks[w * 16 * 32];
  u16* lk1 = &Ks[2048 + w * 16 * 32];
  u16* lv0 = &Vt[w * 16 * 32];
  u16* lv1 = &Vt[2048 + w * 16 * 32];

  for (int j = 0; j <= qt0; ++j) {
    const size_t koff = (size_t)j * 4096;  // j*64 keys * 64 dh
    const size_t voff = (size_t)j * 64;    // j*64 keys along VT rows
    gld16(gk + koff,      lk0);            // K panel 0 (dh 0..31)
    gld16(gk + koff + 32, lk1);            // K panel 1 (dh 32..63)
    gld16(gv + voff,      lv0);            // V keys 0..31
    gld16(gv + voff + 32, lv1);            // V keys 32..63
    __syncthreads();

    ATTN_STEP(0, Pw0, qt0);
    if (j <= qt1) ATTN_STEP(1, Pw1, qt1);   // block-uniform scalar branch
    __syncthreads();
  }

  #pragma unroll
  for (int t = 0; t < 2; ++t) {
    const int qtt = t ? qt1 : qt0;
    #pragma unroll
    for (int r = 0; r < 4; ++r) {
      const float inv = __builtin_amdgcn_rcpf(liacc[t][r]);
      const int sq = qtt * 64 + w * 16 + quad * 4 + r;
      #pragma unroll
      for (int dt = 0; dt < 4; ++dt)
        out[(size_t)(b * 2048 + sq) * 1024 + h * 64 + dt * 16 + l15] =
            f2bf(O[t][dt][r] * inv);
    }
  }
}

extern "C" void kernel_launch(void* const* d_in, const int* in_sizes, int n_in,
                              void* d_out, int out_size, void* d_ws, size_t ws_size,
                              hipStream_t stream) {
  (void)in_sizes; (void)n_in; (void)out_size; (void)ws_size;
  const float* x  = (const float*)d_in[0];
  const float* Wq = (const float*)d_in[1];
  const float* Wk = (const float*)d_in[2];
  const float* Wv = (const float*)d_in[3];
  const float* Wo = (const float*)d_in[4];
  float* out = (float*)d_out;

  // workspace (u16 elems), 72 MB:
  // [0)        xb (x bf16)  -- dead after QKV gemm; reused as AO
  // [8388608)  Qb   [16777216) Kb   [25165824) VT ([b,h,dh,s], direct)
  // [33554432) Wqb,Wkb,Wvb,Wob
  u16* W16 = (u16*)d_ws;
  u16* xb  = W16;
  u16* AO  = W16;                 // alias: x dead after QKV gemm
  u16* Qb  = W16 + 8388608;
  u16* Kb  = W16 + 16777216;
  u16* VT  = W16 + 25165824;
  u16* Wqb = W16 + 33554432;
  u16* Wkb = Wqb + 1048576;
  u16* Wvb = Wkb + 1048576;
  u16* Wob = Wvb + 1048576;

  dim3 blk(256);
  cvt_all<<<dim3(6144), blk, 0, stream>>>(x, xb, Wq, Wqb, Wk, Wkb,
                                          Wv, Wvb, Wo, Wob);
  gemm97<true ><<<dim3(64, 8, 3), blk, 0, stream>>>(
      xb, Wqb, Wkb, Wvb, Qb, Kb, VT, nullptr);
  attn_kernel<<<dim3(16, 64), blk, 0, stream>>>(Qb, Kb, VT, AO);
  gemm97<false><<<dim3(64, 8, 1), blk, 0, stream>>>(
      AO, Wob, Wob, Wob, nullptr, nullptr, nullptr, out);
}

// Round 7
// 298.286 us; speedup vs baseline: 1.0118x; 1.0118x over previous
//
#include <hip/hip_runtime.h>

typedef __attribute__((ext_vector_type(8))) short s16x8;
typedef __attribute__((ext_vector_type(4))) short s16x4;
typedef __attribute__((ext_vector_type(4))) float f32x4;
typedef unsigned short u16;
typedef unsigned int u32;
typedef unsigned long long u64;

__device__ __forceinline__ u16 f2bf(float f) {
  unsigned u = __builtin_bit_cast(unsigned, f);
  return (u16)((u + 0x7fffu + ((u >> 16) & 1u)) >> 16);  // RNE fp32->bf16
}

// 0.125 (1/sqrt(dh)) * log2(e): scores in log2 domain for v_exp_f32
#define QSCALE 0.18033688011112042f

// async global->LDS, 16B per lane; LDS dst = wave-uniform base + lane*16
__device__ __forceinline__ void gld16(const u16* g, u16* l) {
  __builtin_amdgcn_global_load_lds(
      (const __attribute__((address_space(1))) void*)g,
      (__attribute__((address_space(3))) void*)l, 16, 0, 0);
}

// v_perm: D = [bf16(a) | bf16(b)<<16] by byte-select (truncating pack, 1 op)
__device__ __forceinline__ u32 pack_trunc(float a, float b) {
  return __builtin_amdgcn_perm(__builtin_bit_cast(u32, b),
                               __builtin_bit_cast(u32, a), 0x07060302u);
}

// ---------------------------------------------------------------------------
// fp32 -> bf16 convert, all five tensors in ONE launch.
// ---------------------------------------------------------------------------
__global__ __launch_bounds__(256)
void cvt_all(const float* __restrict__ x,  u16* __restrict__ xb,
             const float* __restrict__ w0, u16* __restrict__ w0b,
             const float* __restrict__ w1, u16* __restrict__ w1b,
             const float* __restrict__ w2, u16* __restrict__ w2b,
             const float* __restrict__ w3, u16* __restrict__ w3b)
{
  int bb = blockIdx.x;
  const float* src; u16* dst; int i;
  if (bb < 4096)      { src = x;  dst = xb;  i = bb * 256 + threadIdx.x; }
  else if (bb < 4608) { src = w0; dst = w0b; i = (bb - 4096) * 256 + threadIdx.x; }
  else if (bb < 5120) { src = w1; dst = w1b; i = (bb - 4608) * 256 + threadIdx.x; }
  else if (bb < 5632) { src = w2; dst = w2b; i = (bb - 5120) * 256 + threadIdx.x; }
  else                { src = w3; dst = w3b; i = (bb - 5632) * 256 + threadIdx.x; }
  f32x4 a = ((const f32x4*)src)[2 * i];
  f32x4 b = ((const f32x4*)src)[2 * i + 1];
  s16x8 pk;
  pk[0] = (short)f2bf(a[0]); pk[1] = (short)f2bf(a[1]);
  pk[2] = (short)f2bf(a[2]); pk[3] = (short)f2bf(a[3]);
  pk[4] = (short)f2bf(b[0]); pk[5] = (short)f2bf(b[1]);
  pk[6] = (short)f2bf(b[2]); pk[7] = (short)f2bf(b[3]);
  ((s16x8*)dst)[i] = pk;
}

// ---------------------------------------------------------------------------
// m97-structure GEMM. Grid: (m-tiles, n-tiles, z); m-tile on x -> XCD-pinned.
// OUT_QKV epilogue layouts (all bf16):
//   bz=0: Q  [bh][s][dh] (pre-scaled by QSCALE)
//   bz=1: K  attn-tile layout [bh][tile][dh>>5][slot][dh&31],
//         slot=(key&3)*16+(key>>2)  (the attn LDS layout, baked in)
//   bz=2: V  attn-tile layout [bh][tile][key>>5][d][key&31], packed u64
//         stores (r sweeps 4 consecutive keys)
// ---------------------------------------------------------------------------
template<bool OUT_QKV>
__global__ __launch_bounds__(256)
void gemm97(const u16* __restrict__ A,
            const u16* __restrict__ B0, const u16* __restrict__ B1,
            const u16* __restrict__ B2,
            u16* __restrict__ o0, u16* __restrict__ o1, u16* __restrict__ o2,
            float* __restrict__ oF)
{
  const int by = blockIdx.x;   // m-tile (XCD-pinned)
  const int bx = blockIdx.y;   // n-tile
  const int bz = blockIdx.z;
  const u16* B = (bz == 0) ? B0 : ((bz == 1) ? B1 : B2);
  u16* oQ = (bz == 0) ? o0 : ((bz == 1) ? o1 : o2);

  __shared__ u16 As[128 * 32];
  __shared__ u16 Bs[128 * 32];

  const int tid  = threadIdx.x;
  const int w    = tid >> 6;
  const int lane = tid & 63;
  const int quad = lane >> 4;
  const int l15  = lane & 15;
  const int wm   = (w >> 1) * 64;
  const int wn   = (w & 1) * 64;

  const int arb  = w * 32;
  const int srow = lane >> 2;
  const int scol = (lane & 3) * 8;
  const u16* ga = A + (size_t)(by * 128 + arb + srow) * 1024 + scol;
  const u16* gb = B + (size_t)(bx * 128 + arb + srow) * 1024 + scol;
  u16* la0 = &As[arb * 32];
  u16* la1 = &As[(arb + 16) * 32];
  u16* lb0 = &Bs[arb * 32];
  u16* lb1 = &Bs[(arb + 16) * 32];

  f32x4 acc[4][4];
  #pragma unroll
  for (int i = 0; i < 4; ++i)
    #pragma unroll
    for (int j = 0; j < 4; ++j)
      acc[i][j] = (f32x4){0.f, 0.f, 0.f, 0.f};

  for (int k0 = 0; k0 < 1024; k0 += 32) {
    gld16(ga + k0,               la0);
    gld16(ga + k0 + 16 * 1024,   la1);
    gld16(gb + k0,               lb0);
    gld16(gb + k0 + 16 * 1024,   lb1);
    __syncthreads();

    s16x8 af[4], bf[4];
    #pragma unroll
    for (int i = 0; i < 4; ++i)
      af[i] = *(const s16x8*)&As[(wm + i * 16 + l15) * 32 + quad * 8];
    #pragma unroll
    for (int i = 0; i < 4; ++i)
      bf[i] = *(const s16x8*)&Bs[(wn + i * 16 + l15) * 32 + quad * 8];
    #pragma unroll
    for (int mt = 0; mt < 4; ++mt)
      #pragma unroll
      for (int nt = 0; nt < 4; ++nt)
        acc[mt][nt] = __builtin_amdgcn_mfma_f32_16x16x32_bf16(
            af[mt], bf[nt], acc[mt][nt], 0, 0, 0);
    __syncthreads();
  }

  // epilogue: C/D layout col = lane&15, row = quad*4 + reg
  #pragma unroll
  for (int mt = 0; mt < 4; ++mt)
    #pragma unroll
    for (int nt = 0; nt < 4; ++nt) {
      const int row0 = by * 128 + wm + mt * 16 + quad * 4;
      const int col  = bx * 128 + wn + nt * 16 + l15;
      if (OUT_QKV) {
        const int b = row0 >> 11, s0 = row0 & 2047;
        const int hh = col >> 6, d = col & 63;
        const size_t hb = (size_t)(b * 16 + hh) * 131072;
        if (bz == 2) {
          // V tile layout, 4 consecutive keys -> one u64 store
          const int tile = s0 >> 6, key0 = s0 & 63;
          const u64 pk = (u64)f2bf(acc[mt][nt][0])
                       | ((u64)f2bf(acc[mt][nt][1]) << 16)
                       | ((u64)f2bf(acc[mt][nt][2]) << 32)
                       | ((u64)f2bf(acc[mt][nt][3]) << 48);
          *(u64*)&oQ[hb + tile * 4096 + (key0 >> 5) * 2048 + d * 32 + (key0 & 31)] = pk;
        } else if (bz == 1) {
          #pragma unroll
          for (int r = 0; r < 4; ++r) {
            const int s = s0 + r, tile = s >> 6, key = s & 63;
            const int slot = (key & 3) * 16 + (key >> 2);
            oQ[hb + tile * 4096 + (d >> 5) * 2048 + slot * 32 + (d & 31)] =
                f2bf(acc[mt][nt][r]);
          }
        } else {
          #pragma unroll
          for (int r = 0; r < 4; ++r)
            oQ[hb + (size_t)(s0 + r) * 64 + d] = f2bf(acc[mt][nt][r] * QSCALE);
        }
      } else {
        #pragma unroll
        for (int r = 0; r < 4; ++r)
          oF[(size_t)(row0 + r) * 1024 + col] = acc[mt][nt][r];
      }
    }
}

// ---------------------------------------------------------------------------
// Causal flash attention, pipelined K-loop.
// Block pi owns q-tiles {31-pi, pi}; every wave does 16 rows of each
// (compile-time tile index). K double-buffered via gld16 (prefetch j+1 at
// iteration top); V single-buffered via gld16, awaited at the mid barrier
// (its DMA hides behind QK+softmax). K/V global layouts are the attn tile
// layouts written by the GEMM epilogue -> staging is an identity copy,
// fully coalesced 1KB per gld16. Q frags load straight from global.
// P scratch 64 rows x stride 68 (u64-aligned, ~2-way banks), reused for
// both tiles (same-wave write->read ordering).
// LDS 33.3KB -> 4 blocks/CU.
// ---------------------------------------------------------------------------
#define ATTN_QKP(t, qtt)                                                       \
  do {                                                                         \
    f32x4 S[4];                                                                \
    _Pragma("unroll")                                                          \
    for (int nt = 0; nt < 4; ++nt) {                                           \
      s16x8 b0 = *(const s16x8*)&Ks[(nt * 16 + l15) * 32 + quad * 8];          \
      s16x8 b1 = *(const s16x8*)&Ks[2048 + (nt * 16 + l15) * 32 + quad * 8];   \
      f32x4 z = (f32x4){0.f, 0.f, 0.f, 0.f};                                   \
      z = __builtin_amdgcn_mfma_f32_16x16x32_bf16(aq[t][0], b0, z, 0, 0, 0);   \
      z = __builtin_amdgcn_mfma_f32_16x16x32_bf16(aq[t][1], b1, z, 0, 0, 0);   \
      S[nt] = z;                                                               \
    }                                                                          \
    if (j == (qtt)) {                                                          \
      _Pragma("unroll")                                                        \
      for (int nt = 0; nt < 4; ++nt)                                           \
        _Pragma("unroll")                                                      \
        for (int r = 0; r < 4; ++r) {                                          \
          const int kg = 4 * l15 + nt;                                         \
          const int qg = w * 16 + quad * 4 + r;                                \
          if (kg > qg) S[nt][r] = -1e30f;                                      \
        }                                                                      \
    }                                                                          \
    _Pragma("unroll")                                                          \
    for (int r = 0; r < 4; ++r) {                                              \
      float rm = fmaxf(fmaxf(S[0][r], S[1][r]), fmaxf(S[2][r], S[3][r]));      \
      _Pragma("unroll")                                                        \
      for (int off = 1; off < 16; off <<= 1)                                   \
        rm = fmaxf(rm, __shfl_xor(rm, off, 64));                               \
      const float mold = mi[t][r];                                             \
      const float mnew = fmaxf(mold, rm);                                      \
      const float alpha = __builtin_amdgcn_exp2f(mold - mnew);                 \
      mi[t][r] = mnew;                                                         \
      const float p0 = __builtin_amdgcn_exp2f(S[0][r] - mnew);                 \
      const float p1 = __builtin_amdgcn_exp2f(S[1][r] - mnew);                 \
      const float p2 = __builtin_amdgcn_exp2f(S[2][r] - mnew);                 \
      const float p3 = __builtin_amdgcn_exp2f(S[3][r] - mnew);                 \
      liacc[t][r] *= alpha;                                                    \
      _Pragma("unroll")                                                        \
      for (int dt = 0; dt < 4; ++dt) O[t][dt][r] *= alpha;                     \
      const u64 pk = (u64)pack_trunc(p0, p1) |                                 \
                     ((u64)pack_trunc(p2, p3) << 32);                          \
      *(u64*)&Pw[(quad * 4 + r) * 68 + 4 * l15] = pk;                          \
    }                                                                          \
  } while (0)

#define ATTN_PV(t)                                                             \
  do {                                                                         \
    s16x8 a0 = *(const s16x8*)&Pw[l15 * 68 + quad * 8];                        \
    s16x8 a1 = *(const s16x8*)&Pw[l15 * 68 + 32 + quad * 8];                   \
    liacc[t] = __builtin_amdgcn_mfma_f32_16x16x32_bf16(a0, ones, liacc[t], 0, 0, 0); \
    liacc[t] = __builtin_amdgcn_mfma_f32_16x16x32_bf16(a1, ones, liacc[t], 0, 0, 0); \
    _Pragma("unroll")                                                          \
    for (int dt = 0; dt < 4; ++dt) {                                           \
      s16x8 b0 = *(const s16x8*)&Vbuf[(dt * 16 + l15) * 32 + quad * 8];        \
      s16x8 b1 = *(const s16x8*)&Vbuf[2048 + (dt * 16 + l15) * 32 + quad * 8]; \
      O[t][dt] = __builtin_amdgcn_mfma_f32_16x16x32_bf16(a0, b0, O[t][dt], 0, 0, 0); \
      O[t][dt] = __builtin_amdgcn_mfma_f32_16x16x32_bf16(a1, b1, O[t][dt], 0, 0, 0); \
    }                                                                          \
  } while (0)

__global__ __launch_bounds__(256, 4)
void attn_kernel(const u16* __restrict__ Qg, const u16* __restrict__ Ktg,
                 const u16* __restrict__ Vtg, u16* __restrict__ out)
{
  const int pi = blockIdx.x;
  const int bh = blockIdx.y;
  const int b = bh >> 4, h = bh & 15;
  const int qt0 = 31 - pi;            // heavy tile
  const int qt1 = pi;                 // light tile

  __shared__ u16 Pl[64 * 68];         // P scratch, per-wave 16-row regions
  __shared__ u16 Kbuf[2][4096];       // K tile double-buffer (attn layout)
  __shared__ u16 Vbuf[4096];          // V tile single-buffer (attn layout)

  const int tid = threadIdx.x;
  const int w = tid >> 6, lane = tid & 63, quad = lane >> 4, l15 = lane & 15;
  const size_t base = (size_t)bh * 131072;
  const u16* Kt = Ktg + base;
  const u16* Vt = Vtg + base;

  // prologue: stage tile 0 (K -> Kbuf[0], V -> Vbuf); identity copies
  {
    const u16* gk = Kt + w * 1024 + lane * 8;
    const u16* gv = Vt + w * 1024 + lane * 8;
    gld16(gk,       &Kbuf[0][w * 1024]);
    gld16(gk + 512, &Kbuf[0][w * 1024 + 512]);
    gld16(gv,       &Vbuf[w * 1024]);
    gld16(gv + 512, &Vbuf[w * 1024 + 512]);
  }

  // Q fragments straight from global (no LDS staging)
  s16x8 aq[2][2];
  #pragma unroll
  for (int t = 0; t < 2; ++t) {
    const int qtt = t ? qt1 : qt0;
    #pragma unroll
    for (int ks = 0; ks < 2; ++ks)
      aq[t][ks] = *(const s16x8*)(Qg + base +
          (size_t)(qtt * 64 + w * 16 + l15) * 64 + ks * 32 + quad * 8);
  }

  u16* Pw = &Pl[(w * 16) * 68];

  s16x8 ones;
  #pragma unroll
  for (int e = 0; e < 8; ++e) ones[e] = (short)0x3F80;

  f32x4 O[2][4], liacc[2];
  float mi[2][4];
  #pragma unroll
  for (int t = 0; t < 2; ++t) {
    #pragma unroll
    for (int dt = 0; dt < 4; ++dt) O[t][dt] = (f32x4){0.f, 0.f, 0.f, 0.f};
    liacc[t] = (f32x4){0.f, 0.f, 0.f, 0.f};
    #pragma unroll
    for (int r = 0; r < 4; ++r) mi[t][r] = -1e30f;
  }

  for (int j = 0; j <= qt0; ++j) {
    __syncthreads();                          // B1: K(j) ready; V/K bufs free
    const u16* Ks = Kbuf[j & 1];
    if (j < qt0) {                            // prefetch K(j+1)
      const u16* g = Kt + (size_t)(j + 1) * 4096 + w * 1024 + lane * 8;
      u16* l = &Kbuf[(j + 1) & 1][w * 1024];
      gld16(g, l);
      gld16(g + 512, l + 512);
    }
    if (j > 0) {                              // stage V(j); awaited at B2
      const u16* g = Vt + (size_t)j * 4096 + w * 1024 + lane * 8;
      gld16(g, &Vbuf[w * 1024]);
      gld16(g + 512, &Vbuf[w * 1024 + 512]);
    }

    ATTN_QKP(0, qt0);                         // hides V (and next-K) DMA
    __syncthreads();                          // B2: V(j) ready
    ATTN_PV(0);
    if (j <= qt1) {                           // block-uniform scalar branch
      ATTN_QKP(1, qt1);
      ATTN_PV(1);                             // P reused: same-wave ordering
    }
  }

  #pragma unroll
  for (int t = 0; t < 2; ++t) {
    const int qtt = t ? qt1 : qt0;
    #pragma unroll
    for (int r = 0; r < 4; ++r) {
      const float inv = __builtin_amdgcn_rcpf(liacc[t][r]);
      const int sq = qtt * 64 + w * 16 + quad * 4 + r;
      #pragma unroll
      for (int dt = 0; dt < 4; ++dt)
        out[(size_t)(b * 2048 + sq) * 1024 + h * 64 + dt * 16 + l15] =
            f2bf(O[t][dt][r] * inv);
    }
  }
}

extern "C" void kernel_launch(void* const* d_in, const int* in_sizes, int n_in,
                              void* d_out, int out_size, void* d_ws, size_t ws_size,
                              hipStream_t stream) {
  (void)in_sizes; (void)n_in; (void)out_size; (void)ws_size;
  const float* x  = (const float*)d_in[0];
  const float* Wq = (const float*)d_in[1];
  const float* Wk = (const float*)d_in[2];
  const float* Wv = (const float*)d_in[3];
  const float* Wo = (const float*)d_in[4];
  float* out = (float*)d_out;

  // workspace (u16 elems), 72 MB:
  // [0)        xb (x bf16)  -- dead after QKV gemm; reused as AO
  // [8388608)  Qb [bh][s][dh]
  // [16777216) Kb (attn tile layout)
  // [25165824) Vb (attn tile layout)
  // [33554432) Wqb,Wkb,Wvb,Wob
  u16* W16 = (u16*)d_ws;
  u16* xb  = W16;
  u16* AO  = W16;                 // alias: x dead after QKV gemm
  u16* Qb  = W16 + 8388608;
  u16* Kb  = W16 + 16777216;
  u16* Vb  = W16 + 25165824;
  u16* Wqb = W16 + 33554432;
  u16* Wkb = Wqb + 1048576;
  u16* Wvb = Wkb + 1048576;
  u16* Wob = Wvb + 1048576;

  dim3 blk(256);
  cvt_all<<<dim3(6144), blk, 0, stream>>>(x, xb, Wq, Wqb, Wk, Wkb,
                                          Wv, Wvb, Wo, Wob);
  gemm97<true ><<<dim3(64, 8, 3), blk, 0, stream>>>(
      xb, Wqb, Wkb, Wvb, Qb, Kb, Vb, nullptr);
  attn_kernel<<<dim3(16, 64), blk, 0, stream>>>(Qb, Kb, Vb, AO);
  gemm97<false><<<dim3(64, 8, 1), blk, 0, stream>>>(
      AO, Wob, Wob, Wob, nullptr, nullptr, nullptr, out);
}